// Round 4
// baseline (79.218 us; speedup 1.0000x reference)
//
#include <hip/hip_runtime.h>
#include <math.h>

// FGN layer, single fused kernel (no workspace, no prep pass):
//   res = (X @ W^T + bias) * g
//   g   = exp(-(Sum_k x^2*s^2 - 2*x*c*s^2 + c^2*s^2)),  s = min(ic, 1e8)
// Four bf16 MFMA streams over K=256, fragments converted fp32->bf16 in
// registers straight from the L2-resident inputs:
//   accL += (x , w)        accG += (x , -2*c*s^2)
//   accG += (x², s^2)      accC += (1 , c^2*s^2)     (per-n constant)
// Grid 32x32 blocks x 256 thr; each block one 32x32 tile, 4 waves split
// K=256 into 4x64; partials reduced via LDS (stride 17 = conflict-free),
// fused exp/bias epilogue. Single launch removes the prep->main L3 round
// trip through the poison-thrashed cache and one launch gap.

typedef __attribute__((ext_vector_type(8))) short short8;
typedef __attribute__((ext_vector_type(4))) float floatx4;

#define BDIM   1024
#define INDIM  256
#define OUTDIM 1024

__device__ __forceinline__ unsigned short f2bf(float f) {
    union { float f; unsigned u; } v; v.f = f;
    unsigned r = v.u + 0x7FFFu + ((v.u >> 16) & 1u);   // RNE
    return (unsigned short)(r >> 16);
}

__device__ __forceinline__ void load8(const float* __restrict__ p, float f[8]) {
    float4 v0 = *(const float4*)p;
    float4 v1 = *(const float4*)(p + 4);
    f[0]=v0.x; f[1]=v0.y; f[2]=v0.z; f[3]=v0.w;
    f[4]=v1.x; f[5]=v1.y; f[6]=v1.z; f[7]=v1.w;
}

__device__ __forceinline__ short8 pack8(const float f[8]) {
    short8 r;
    #pragma unroll
    for (int i = 0; i < 8; ++i) r[i] = (short)f2bf(f[i]);
    return r;
}

#define MFMA __builtin_amdgcn_mfma_f32_16x16x32_bf16

__global__ __launch_bounds__(256)
void fgn_fused(const float* __restrict__ X, const float* __restrict__ W,
               const float* __restrict__ Bias, const float* __restrict__ C,
               const float* __restrict__ IC, float* __restrict__ Out)
{
    const int n0   = blockIdx.x * 32;
    const int m0   = blockIdx.y * 32;
    const int t    = threadIdx.x;
    const int w    = t >> 6;          // wave id = K chunk (64 k each)
    const int lane = t & 63;
    const int r    = lane & 15;
    const int q    = lane >> 4;

    __shared__ float sL[4 * 64 * 17];
    __shared__ float sG[4 * 64 * 17];
    __shared__ float sC[4][32];

    floatx4 zero = {0.f, 0.f, 0.f, 0.f};
    floatx4 accL[2][2] = {{zero, zero}, {zero, zero}};
    floatx4 accG[2][2] = {{zero, zero}, {zero, zero}};
    floatx4 accC[2]    = {zero, zero};

    short8 ones;
    #pragma unroll
    for (int i = 0; i < 8; ++i) ones[i] = (short)0x3F80;   // bf16 1.0

    #pragma unroll
    for (int kk = 0; kk < 2; ++kk) {
        const int k = w * 64 + kk * 32 + q * 8;
        // ---- A-side fragments: x and x^2 (rows m0+mt*16+r) ----
        short8 a0[2], a2[2];
        #pragma unroll
        for (int mt = 0; mt < 2; ++mt) {
            float x[8], xs[8];
            load8(&X[(size_t)(m0 + mt * 16 + r) * INDIM + k], x);
            #pragma unroll
            for (int i = 0; i < 8; ++i) xs[i] = x[i] * x[i];
            a0[mt] = pack8(x);
            a2[mt] = pack8(xs);
        }
        // ---- B-side per n-tile: w, -2cs^2, s^2, c^2 s^2 ----
        #pragma unroll
        for (int nt = 0; nt < 2; ++nt) {
            const size_t ro = (size_t)(n0 + nt * 16 + r) * INDIM + k;
            float wv[8], cv[8], iv[8], g1[8], g2[8], g3[8];
            load8(&W[ro],  wv);
            load8(&C[ro],  cv);
            load8(&IC[ro], iv);
            #pragma unroll
            for (int i = 0; i < 8; ++i) {
                float s  = fminf(iv[i], 1e8f);
                float qq = s * s;
                g2[i] = qq;
                g1[i] = -2.f * cv[i] * qq;
                g3[i] = cv[i] * cv[i] * qq;
            }
            short8 wf = pack8(wv), f1 = pack8(g1), f2 = pack8(g2), f3 = pack8(g3);
            accL[0][nt] = MFMA(a0[0], wf, accL[0][nt], 0, 0, 0);
            accL[1][nt] = MFMA(a0[1], wf, accL[1][nt], 0, 0, 0);
            accG[0][nt] = MFMA(a0[0], f1, accG[0][nt], 0, 0, 0);
            accG[1][nt] = MFMA(a0[1], f1, accG[1][nt], 0, 0, 0);
            accG[0][nt] = MFMA(a2[0], f2, accG[0][nt], 0, 0, 0);
            accG[1][nt] = MFMA(a2[1], f2, accG[1][nt], 0, 0, 0);
            accC[nt]    = MFMA(ones,  f3, accC[nt],    0, 0, 0);
        }
    }

    // ---- partials to LDS (stride 17 words: conflict-free) ----
    #pragma unroll
    for (int mt = 0; mt < 2; ++mt)
        #pragma unroll
        for (int nt = 0; nt < 2; ++nt)
            #pragma unroll
            for (int reg = 0; reg < 4; ++reg) {
                const int f = mt * 8 + nt * 4 + reg;
                sG[(w * 64 + lane) * 17 + f] = accG[mt][nt][reg];
                sL[(w * 64 + lane) * 17 + f] = accL[mt][nt][reg];
            }
    if (q == 0) {                       // accC rows all equal; reg 0 of q==0
        sC[w][r]      = accC[0][0];
        sC[w][16 + r] = accC[1][0];
    }
    __syncthreads();

    // ---- reduce + epilogue: thread t -> frag slots f = w*4..w*4+3 at lane ----
    const int l  = lane;
    const int li = l & 15;
    float cz0 = 0.f, cz1 = 0.f;
    #pragma unroll
    for (int ww = 0; ww < 4; ++ww) { cz0 += sC[ww][li]; cz1 += sC[ww][16 + li]; }
    const float bias0 = Bias[n0 + li], bias1 = Bias[n0 + 16 + li];
    float* OutR = Out;
    float* OutG = Out + (size_t)BDIM * OUTDIM;
    #pragma unroll
    for (int j = 0; j < 4; ++j) {
        const int f = w * 4 + j;
        float Ls = 0.f, Gs = 0.f;
        #pragma unroll
        for (int ww = 0; ww < 4; ++ww) {
            Ls += sL[(ww * 64 + l) * 17 + f];
            Gs += sG[(ww * 64 + l) * 17 + f];
        }
        const int mt = f >> 3, nt = (f >> 2) & 1, reg = f & 3;
        const int m = m0 + mt * 16 + (l >> 4) * 4 + reg;
        const int n = n0 + nt * 16 + li;
        const float g   = expf(-(Gs + (nt ? cz1 : cz0)));
        const float res = (Ls + (nt ? bias1 : bias0)) * g;
        OutR[(size_t)m * OUTDIM + n] = res;
        OutG[(size_t)m * OUTDIM + n] = g;
    }
}

extern "C" void kernel_launch(void* const* d_in, const int* in_sizes, int n_in,
                              void* d_out, int out_size, void* d_ws, size_t ws_size,
                              hipStream_t stream) {
    const float* X    = (const float*)d_in[0];
    const float* W    = (const float*)d_in[1];
    const float* Bias = (const float*)d_in[2];
    const float* C    = (const float*)d_in[3];
    const float* IC   = (const float*)d_in[4];
    float* Out = (float*)d_out;

    dim3 grid(OUTDIM / 32, BDIM / 32);
    fgn_fused<<<grid, 256, 0, stream>>>(X, W, Bias, C, IC, Out);
}

// Round 5
// 71.584 us; speedup vs baseline: 1.1066x; 1.1066x over previous
//
#include <hip/hip_runtime.h>
#include <hip/hip_bf16.h>
#include <math.h>

// FGN layer, single fused kernel with LDS-staged converted bf16 tiles:
//   res = (X @ W^T + bias) * g
//   g   = exp(-(sum_k x^2*s^2 - 2*x*c*s^2 + c^2*s^2)),  s = min(ic, 1e8)
// Block = 64m x 32n tile, 256 thr (4 waves; wave i owns m-rows i*16..i*16+15).
// K staged in tiles of 64: fp32 loads (coalesced 256 B rows) -> convert in
// registers -> bf16 LDS tiles [x, x^2 | w, -2cs^2, s^2, c^2s^2] (stride 72
// ushort = 144 B: 16B-aligned b128, <=2-way bank alias = free). 4 MFMA
// streams; per-z constant via all-ones A fragment so no cross-wave
// reduction: epilogue straight from registers. Grid 512 = 2 blocks/CU.

typedef __attribute__((ext_vector_type(8))) short short8;
typedef __attribute__((ext_vector_type(4))) float floatx4;

#define MFMA __builtin_amdgcn_mfma_f32_16x16x32_bf16
#define INDIM 256
#define OUTD  1024
#define BD    1024
#define TM 64
#define TN 32
#define TK 64
#define KSTR 72   // LDS row stride in ushort (144 B = 9*16 -> b128-aligned rows)

__device__ __forceinline__ unsigned pkbf(float a, float b) {
    union { __hip_bfloat162 h; unsigned u; } v;
    v.h = __float22bfloat162_rn(make_float2(a, b));
    return v.u;
}

__global__ __launch_bounds__(256)
void fgn_fused(const float* __restrict__ X, const float* __restrict__ W,
               const float* __restrict__ Bias, const float* __restrict__ C,
               const float* __restrict__ IC, float* __restrict__ Out)
{
    __shared__ __align__(16) unsigned short As [TM * KSTR];
    __shared__ __align__(16) unsigned short As2[TM * KSTR];
    __shared__ __align__(16) unsigned short Bw [TN * KSTR];
    __shared__ __align__(16) unsigned short Bg1[TN * KSTR];
    __shared__ __align__(16) unsigned short Bg2[TN * KSTR];
    __shared__ __align__(16) unsigned short Bg3[TN * KSTR];

    const int n0   = blockIdx.x * TN;
    const int m0   = blockIdx.y * TM;
    const int t    = threadIdx.x;
    const int w    = t >> 6;           // wave id: owns m-rows w*16..w*16+15
    const int lane = t & 63;
    const int r    = lane & 15;
    const int q    = lane >> 4;

    // staging coordinates
    const int arow = t >> 2;           // 0..63  (A tile row)
    const int akq  = (t & 3) << 4;     // 0,16,32,48 (16 k's per thread)
    const int bz   = t >> 3;           // 0..31  (B tile row)
    const int bkq  = (t & 7) << 3;     // 0..56  (8 k's per thread)

    floatx4 zero = {0.f, 0.f, 0.f, 0.f};
    floatx4 accL[2] = {zero, zero};
    floatx4 accG[2] = {zero, zero};
    floatx4 accC[2] = {zero, zero};
    short8 ones;
    #pragma unroll
    for (int i = 0; i < 8; ++i) ones[i] = (short)0x3F80;   // bf16 1.0

    for (int k0 = 0; k0 < INDIM; k0 += TK) {
        // ---- global loads for this K-tile (issue before barrier: overlap prior compute)
        float4 xa[4];
        {
            const float* xp = &X[(size_t)(m0 + arow) * INDIM + k0 + akq];
            #pragma unroll
            for (int i = 0; i < 4; ++i) xa[i] = ((const float4*)xp)[i];
        }
        const size_t bo = (size_t)(n0 + bz) * INDIM + k0 + bkq;
        float4 wv0 = *(const float4*)&W[bo],  wv1 = *(const float4*)&W[bo + 4];
        float4 cv0 = *(const float4*)&C[bo],  cv1 = *(const float4*)&C[bo + 4];
        float4 iv0 = *(const float4*)&IC[bo], iv1 = *(const float4*)&IC[bo + 4];

        __syncthreads();   // previous tile's compute done before LDS overwrite

        // ---- A: stage bf16(x), bf16(x^2)
        {
            const float* xf = (const float*)xa;
            unsigned ux[8], ux2[8];
            #pragma unroll
            for (int i = 0; i < 8; ++i) {
                float e0 = xf[2*i], e1 = xf[2*i+1];
                ux[i]  = pkbf(e0, e1);
                ux2[i] = pkbf(e0 * e0, e1 * e1);
            }
            uint4* pa  = (uint4*)&As [arow * KSTR + akq];
            uint4* pa2 = (uint4*)&As2[arow * KSTR + akq];
            pa[0]  = make_uint4(ux[0],  ux[1],  ux[2],  ux[3]);
            pa[1]  = make_uint4(ux[4],  ux[5],  ux[6],  ux[7]);
            pa2[0] = make_uint4(ux2[0], ux2[1], ux2[2], ux2[3]);
            pa2[1] = make_uint4(ux2[4], ux2[5], ux2[6], ux2[7]);
        }
        // ---- B: stage bf16(w), bf16(-2*c*s^2), bf16(s^2), bf16(c^2*s^2)
        {
            float wf[8] = {wv0.x,wv0.y,wv0.z,wv0.w, wv1.x,wv1.y,wv1.z,wv1.w};
            float cf[8] = {cv0.x,cv0.y,cv0.z,cv0.w, cv1.x,cv1.y,cv1.z,cv1.w};
            float f0[8] = {iv0.x,iv0.y,iv0.z,iv0.w, iv1.x,iv1.y,iv1.z,iv1.w};
            float g1[8], g2[8], g3[8];
            #pragma unroll
            for (int i = 0; i < 8; ++i) {
                float s  = fminf(f0[i], 1e8f);
                float qq = s * s;
                g2[i] = qq;
                g1[i] = -2.f * cf[i] * qq;
                g3[i] = cf[i] * cf[i] * qq;
            }
            const int bb = bz * KSTR + bkq;
            *(uint4*)&Bw [bb] = make_uint4(pkbf(wf[0],wf[1]), pkbf(wf[2],wf[3]),
                                           pkbf(wf[4],wf[5]), pkbf(wf[6],wf[7]));
            *(uint4*)&Bg1[bb] = make_uint4(pkbf(g1[0],g1[1]), pkbf(g1[2],g1[3]),
                                           pkbf(g1[4],g1[5]), pkbf(g1[6],g1[7]));
            *(uint4*)&Bg2[bb] = make_uint4(pkbf(g2[0],g2[1]), pkbf(g2[2],g2[3]),
                                           pkbf(g2[4],g2[5]), pkbf(g2[6],g2[7]));
            *(uint4*)&Bg3[bb] = make_uint4(pkbf(g3[0],g3[1]), pkbf(g3[2],g3[3]),
                                           pkbf(g3[4],g3[5]), pkbf(g3[6],g3[7]));
        }
        __syncthreads();

        // ---- compute: 2 k-steps of 32, fragments from LDS
        #pragma unroll
        for (int kk = 0; kk < 2; ++kk) {
            const int ko = kk * 32 + q * 8;
            short8 a0 = *(const short8*)&As [(w * 16 + r) * KSTR + ko];
            short8 a2 = *(const short8*)&As2[(w * 16 + r) * KSTR + ko];
            #pragma unroll
            for (int nt = 0; nt < 2; ++nt) {
                const int br = (nt * 16 + r) * KSTR + ko;
                short8 bwf = *(const short8*)&Bw [br];
                short8 b1f = *(const short8*)&Bg1[br];
                short8 b2f = *(const short8*)&Bg2[br];
                short8 b3f = *(const short8*)&Bg3[br];
                accL[nt] = MFMA(a0,   bwf, accL[nt], 0, 0, 0);
                accG[nt] = MFMA(a0,   b1f, accG[nt], 0, 0, 0);
                accG[nt] = MFMA(a2,   b2f, accG[nt], 0, 0, 0);
                accC[nt] = MFMA(ones, b3f, accC[nt], 0, 0, 0);
            }
        }
    }

    // ---- epilogue straight from registers (wave owns its 16 m-rows)
    float* OutR = Out;
    float* OutG = Out + (size_t)BD * OUTD;
    #pragma unroll
    for (int nt = 0; nt < 2; ++nt) {
        const int n     = n0 + nt * 16 + r;
        const float bias = Bias[n];
        const float cz   = accC[nt][0];   // all rows of ones-MFMA identical
        #pragma unroll
        for (int reg = 0; reg < 4; ++reg) {
            const int m = m0 + w * 16 + q * 4 + reg;
            const float g   = expf(-(accG[nt][reg] + cz));
            const float res = (accL[nt][reg] + bias) * g;
            OutR[(size_t)m * OUTD + n] = res;
            OutG[(size_t)m * OUTD + n] = g;
        }
    }
}

extern "C" void kernel_launch(void* const* d_in, const int* in_sizes, int n_in,
                              void* d_out, int out_size, void* d_ws, size_t ws_size,
                              hipStream_t stream) {
    const float* X    = (const float*)d_in[0];
    const float* W    = (const float*)d_in[1];
    const float* Bias = (const float*)d_in[2];
    const float* C    = (const float*)d_in[3];
    const float* IC   = (const float*)d_in[4];
    float* Out = (float*)d_out;

    dim3 grid(OUTD / TN, BD / TM);   // 32 x 16 = 512 blocks = 2/CU
    fgn_fused<<<grid, 256, 0, stream>>>(X, W, Bias, C, IC, Out);
}

// Round 6
// 71.548 us; speedup vs baseline: 1.1072x; 1.0005x over previous
//
#include <hip/hip_runtime.h>
#include <hip/hip_bf16.h>
#include <math.h>

// FGN layer, single fused kernel with LDS-staged converted bf16 tiles and
// XCD-aware block swizzle:
//   res = (X @ W^T + bias) * g
//   g   = exp(-(sum_k x^2*s^2 - 2*x*c*s^2 + c^2*s^2)),  s = min(ic, 1e8)
// Block = 64m x 32n tile, 256 thr. Swizzle: linear block b -> XCD x=b%8 owns
// n-columns {x, x+8, x+16, x+24} x all 16 m-rows, so per-XCD L2 working set
// is X (1 MB) + WCI slice (384 KB) = 1.4 MB << 4 MB L2. HBM fetch ~11 MB
// instead of ~80 MB of cross-block redundancy (the harness's 256 MB poison
// wipes L2/L3 every iteration, so redundant fetches were HBM-cold).

typedef __attribute__((ext_vector_type(8))) short short8;
typedef __attribute__((ext_vector_type(4))) float floatx4;

#define MFMA __builtin_amdgcn_mfma_f32_16x16x32_bf16
#define INDIM 256
#define OUTD  1024
#define BD    1024
#define TM 64
#define TN 32
#define TK 64
#define KSTR 72   // LDS row stride in ushort (144 B: b128-aligned, <=2-way alias)

__device__ __forceinline__ unsigned pkbf(float a, float b) {
    union { __hip_bfloat162 h; unsigned u; } v;
    v.h = __float22bfloat162_rn(make_float2(a, b));
    return v.u;
}

__global__ __launch_bounds__(256)
void fgn_fused(const float* __restrict__ X, const float* __restrict__ W,
               const float* __restrict__ Bias, const float* __restrict__ C,
               const float* __restrict__ IC, float* __restrict__ Out)
{
    __shared__ __align__(16) unsigned short As [TM * KSTR];
    __shared__ __align__(16) unsigned short As2[TM * KSTR];
    __shared__ __align__(16) unsigned short Bw [TN * KSTR];
    __shared__ __align__(16) unsigned short Bg1[TN * KSTR];
    __shared__ __align__(16) unsigned short Bg2[TN * KSTR];
    __shared__ __align__(16) unsigned short Bg3[TN * KSTR];

    // ---- XCD-aware swizzle: XCD = b % 8 (round-robin dispatch heuristic)
    const int b    = blockIdx.x;      // 0..511
    const int xcd  = b & 7;
    const int i    = b >> 3;          // 0..63
    const int ncol = xcd + 8 * (i & 3);   // 0..31 ; ncol % 8 == xcd
    const int mrow = i >> 2;              // 0..15
    const int n0   = ncol * TN;
    const int m0   = mrow * TM;

    const int t    = threadIdx.x;
    const int w    = t >> 6;           // wave id: owns m-rows w*16..w*16+15
    const int lane = t & 63;
    const int r    = lane & 15;
    const int q    = lane >> 4;

    // staging coordinates
    const int arow = t >> 2;           // 0..63  (A tile row)
    const int akq  = (t & 3) << 4;     // 0,16,32,48
    const int bz   = t >> 3;           // 0..31  (B tile row)
    const int bkq  = (t & 7) << 3;     // 0..56

    floatx4 zero = {0.f, 0.f, 0.f, 0.f};
    floatx4 accL[2] = {zero, zero};
    floatx4 accG[2] = {zero, zero};
    floatx4 accC[2] = {zero, zero};
    short8 ones;
    #pragma unroll
    for (int iq = 0; iq < 8; ++iq) ones[iq] = (short)0x3F80;   // bf16 1.0

    for (int k0 = 0; k0 < INDIM; k0 += TK) {
        // ---- global loads for this K-tile
        float4 xa[4];
        {
            const float* xp = &X[(size_t)(m0 + arow) * INDIM + k0 + akq];
            #pragma unroll
            for (int j = 0; j < 4; ++j) xa[j] = ((const float4*)xp)[j];
        }
        const size_t bo = (size_t)(n0 + bz) * INDIM + k0 + bkq;
        float4 wv0 = *(const float4*)&W[bo],  wv1 = *(const float4*)&W[bo + 4];
        float4 cv0 = *(const float4*)&C[bo],  cv1 = *(const float4*)&C[bo + 4];
        float4 iv0 = *(const float4*)&IC[bo], iv1 = *(const float4*)&IC[bo + 4];

        __syncthreads();   // previous tile's compute done before LDS overwrite

        // ---- A: stage bf16(x), bf16(x^2)
        {
            const float* xf = (const float*)xa;
            unsigned ux[8], ux2[8];
            #pragma unroll
            for (int j = 0; j < 8; ++j) {
                float e0 = xf[2*j], e1 = xf[2*j+1];
                ux[j]  = pkbf(e0, e1);
                ux2[j] = pkbf(e0 * e0, e1 * e1);
            }
            uint4* pa  = (uint4*)&As [arow * KSTR + akq];
            uint4* pa2 = (uint4*)&As2[arow * KSTR + akq];
            pa[0]  = make_uint4(ux[0],  ux[1],  ux[2],  ux[3]);
            pa[1]  = make_uint4(ux[4],  ux[5],  ux[6],  ux[7]);
            pa2[0] = make_uint4(ux2[0], ux2[1], ux2[2], ux2[3]);
            pa2[1] = make_uint4(ux2[4], ux2[5], ux2[6], ux2[7]);
        }
        // ---- B: stage bf16(w), bf16(-2*c*s^2), bf16(s^2), bf16(c^2*s^2)
        {
            float wf[8] = {wv0.x,wv0.y,wv0.z,wv0.w, wv1.x,wv1.y,wv1.z,wv1.w};
            float cf[8] = {cv0.x,cv0.y,cv0.z,cv0.w, cv1.x,cv1.y,cv1.z,cv1.w};
            float f0[8] = {iv0.x,iv0.y,iv0.z,iv0.w, iv1.x,iv1.y,iv1.z,iv1.w};
            float g1[8], g2[8], g3[8];
            #pragma unroll
            for (int j = 0; j < 8; ++j) {
                float s  = fminf(f0[j], 1e8f);
                float qq = s * s;
                g2[j] = qq;
                g1[j] = -2.f * cf[j] * qq;
                g3[j] = cf[j] * cf[j] * qq;
            }
            const int bb = bz * KSTR + bkq;
            *(uint4*)&Bw [bb] = make_uint4(pkbf(wf[0],wf[1]), pkbf(wf[2],wf[3]),
                                           pkbf(wf[4],wf[5]), pkbf(wf[6],wf[7]));
            *(uint4*)&Bg1[bb] = make_uint4(pkbf(g1[0],g1[1]), pkbf(g1[2],g1[3]),
                                           pkbf(g1[4],g1[5]), pkbf(g1[6],g1[7]));
            *(uint4*)&Bg2[bb] = make_uint4(pkbf(g2[0],g2[1]), pkbf(g2[2],g2[3]),
                                           pkbf(g2[4],g2[5]), pkbf(g2[6],g2[7]));
            *(uint4*)&Bg3[bb] = make_uint4(pkbf(g3[0],g3[1]), pkbf(g3[2],g3[3]),
                                           pkbf(g3[4],g3[5]), pkbf(g3[6],g3[7]));
        }
        __syncthreads();

        // ---- compute: 2 k-steps of 32, fragments from LDS
        #pragma unroll
        for (int kk = 0; kk < 2; ++kk) {
            const int ko = kk * 32 + q * 8;
            short8 a0 = *(const short8*)&As [(w * 16 + r) * KSTR + ko];
            short8 a2 = *(const short8*)&As2[(w * 16 + r) * KSTR + ko];
            #pragma unroll
            for (int nt = 0; nt < 2; ++nt) {
                const int br = (nt * 16 + r) * KSTR + ko;
                short8 bwf = *(const short8*)&Bw [br];
                short8 b1f = *(const short8*)&Bg1[br];
                short8 b2f = *(const short8*)&Bg2[br];
                short8 b3f = *(const short8*)&Bg3[br];
                accL[nt] = MFMA(a0,   bwf, accL[nt], 0, 0, 0);
                accG[nt] = MFMA(a0,   b1f, accG[nt], 0, 0, 0);
                accG[nt] = MFMA(a2,   b2f, accG[nt], 0, 0, 0);
                accC[nt] = MFMA(ones, b3f, accC[nt], 0, 0, 0);
            }
        }
    }

    // ---- epilogue straight from registers (wave owns its 16 m-rows)
    float* OutR = Out;
    float* OutG = Out + (size_t)BD * OUTD;
    #pragma unroll
    for (int nt = 0; nt < 2; ++nt) {
        const int n     = n0 + nt * 16 + r;
        const float bias = Bias[n];
        const float cz   = accC[nt][0];   // all rows of ones-MFMA identical
        #pragma unroll
        for (int reg = 0; reg < 4; ++reg) {
            const int m = m0 + w * 16 + q * 4 + reg;
            const float g   = expf(-(accG[nt][reg] + cz));
            const float res = (accL[nt][reg] + bias) * g;
            OutR[(size_t)m * OUTD + n] = res;
            OutG[(size_t)m * OUTD + n] = g;
        }
    }
}

extern "C" void kernel_launch(void* const* d_in, const int* in_sizes, int n_in,
                              void* d_out, int out_size, void* d_ws, size_t ws_size,
                              hipStream_t stream) {
    const float* X    = (const float*)d_in[0];
    const float* W    = (const float*)d_in[1];
    const float* Bias = (const float*)d_in[2];
    const float* C    = (const float*)d_in[3];
    const float* IC   = (const float*)d_in[4];
    float* Out = (float*)d_out;

    fgn_fused<<<512, 256, 0, stream>>>(X, W, Bias, C, IC, Out);
}